// Round 8
// baseline (170.247 us; speedup 1.0000x reference)
//
#include <hip/hip_runtime.h>
#include <hip/hip_bf16.h>

#define NN 8192
#define CC 256
#define CQK 32
#define JS 4   // pass1 j-splits

using bf16x8 = __attribute__((ext_vector_type(8))) short;
using s16x4  = __attribute__((ext_vector_type(4))) short;
using f32x4  = __attribute__((ext_vector_type(4))) float;
using f32x16 = __attribute__((ext_vector_type(16))) float;

static __device__ __forceinline__ unsigned short f2bf(float x) {
    union { __hip_bfloat16 h; unsigned short u; } cv;
    cv.h = __float2bfloat16(x);
    return cv.u;
}
static __device__ __forceinline__ float bf2f(unsigned short u) {
    union { unsigned short u; __hip_bfloat16 h; } cv;
    cv.u = u;
    return __bfloat162float(cv.h);
}
static __device__ __forceinline__ float fexp2(float x) { return __builtin_amdgcn_exp2f(x); }
static __device__ __forceinline__ int packbf(float lo, float hi) {
    return (int)f2bf(lo) | ((int)f2bf(hi) << 16);
}

// ---------------------------------------------------------------------------
// Kernel 1a: q = (f @ Wqk^T) * sqrt(log2 e), stored hi/lo bf16.
// ---------------------------------------------------------------------------
__global__ __launch_bounds__(256) void proj_q_kernel(
    const float* __restrict__ f, const float* __restrict__ Wqk,
    unsigned short* __restrict__ qhi, unsigned short* __restrict__ qlo)
{
    __shared__ __align__(16) float fl[8][CC];
    const int t  = threadIdx.x;
    const int r0 = blockIdx.x * 8;
    {
        const float4* src = (const float4*)(f + (size_t)r0 * CC);
        float4* dst = (float4*)&fl[0][0];
        dst[t]       = src[t];
        dst[t + 256] = src[t + 256];
    }
    __syncthreads();
    const int cq = t & 31;
    const int rg = t >> 5;
    const float4* w4 = (const float4*)(Wqk + (size_t)cq * CC);
    float a = 0.f;
    for (int k4 = 0; k4 < 64; ++k4) {
        float4 wq = w4[k4];
        const float4 fv = *(const float4*)&fl[rg][k4 * 4];
        a = fmaf(wq.x, fv.x, a);
        a = fmaf(wq.y, fv.y, a);
        a = fmaf(wq.z, fv.z, a);
        a = fmaf(wq.w, fv.w, a);
    }
    a *= 1.2011224087864498f;              // sqrt(log2 e) -> exp2 domain
    unsigned short hh = f2bf(a);
    unsigned short ll = f2bf(a - bf2f(hh));
    qhi[(size_t)(r0 + rg) * CQK + cq] = hh;
    qlo[(size_t)(r0 + rg) * CQK + cq] = ll;
}

// ---------------------------------------------------------------------------
// Kernel 1b: v = f @ Wv^T + bv via bf16 32x32x16 MFMA.
// Output layout vB[i>>3][c][i&7] bf16 -> PV B-frags are coalesced b128 loads.
// ---------------------------------------------------------------------------
__global__ __launch_bounds__(256, 4) void proj_v_kernel(
    const float* __restrict__ f, const float* __restrict__ Wv,
    const float* __restrict__ bv, unsigned short* __restrict__ vB)
{
    const int t    = threadIdx.x;
    const int lane = t & 63;
    const int w    = t >> 6;
    const int l31  = lane & 31;
    const int h    = lane >> 5;
    const int nb   = blockIdx.x * 32;
    const int cb   = w * 64;

    f32x16 acc[2];
#pragma unroll
    for (int cf = 0; cf < 2; ++cf)
#pragma unroll
        for (int r = 0; r < 16; ++r) acc[cf][r] = 0.f;

    const float* frow = f + (size_t)(nb + l31) * CC;
#pragma unroll
    for (int ks = 0; ks < 16; ++ks) {
        const int k0 = ks * 16 + 8 * h;
        float4 a0 = *(const float4*)(frow + k0);
        float4 a1 = *(const float4*)(frow + k0 + 4);
        bf16x8 af;
        af[0] = (short)f2bf(a0.x); af[1] = (short)f2bf(a0.y);
        af[2] = (short)f2bf(a0.z); af[3] = (short)f2bf(a0.w);
        af[4] = (short)f2bf(a1.x); af[5] = (short)f2bf(a1.y);
        af[6] = (short)f2bf(a1.z); af[7] = (short)f2bf(a1.w);
#pragma unroll
        for (int cf = 0; cf < 2; ++cf) {
            const float* wrow = Wv + (size_t)(cb + 32 * cf + l31) * CC + k0;
            float4 b0 = *(const float4*)(wrow);
            float4 b1 = *(const float4*)(wrow + 4);
            bf16x8 bw;
            bw[0] = (short)f2bf(b0.x); bw[1] = (short)f2bf(b0.y);
            bw[2] = (short)f2bf(b0.z); bw[3] = (short)f2bf(b0.w);
            bw[4] = (short)f2bf(b1.x); bw[5] = (short)f2bf(b1.y);
            bw[6] = (short)f2bf(b1.z); bw[7] = (short)f2bf(b1.w);
            acc[cf] = __builtin_amdgcn_mfma_f32_32x32x16_bf16(af, bw, acc[cf], 0, 0, 0);
        }
    }
#pragma unroll
    for (int cf = 0; cf < 2; ++cf) {
        const int cg = cb + 32 * cf + l31;
        const float bvc = bv[cg];
#pragma unroll
        for (int rg = 0; rg < 4; ++rg) {
            const int ib = (nb >> 3) + rg;
            s16x4 pk;
#pragma unroll
            for (int r = 0; r < 4; ++r)
                pk[r] = (short)f2bf(acc[cf][4 * rg + r] + bvc);
            *(s16x4*)(vB + ((size_t)ib * CC + cg) * 8 + 4 * h) = pk;
        }
    }
}

// ---------------------------------------------------------------------------
// Kernel 2: per-i partial denominators over a j-range. NO max tracking:
// exp2-domain energies are bounded (|e| << 127), so s = sum_j exp2(e) is
// f32-safe. Saves ~35 VALU/tile vs online-max.
// grid (NN/32)*JS x 256 thr (4 waves, each 1/(4*JS) of j).
// ---------------------------------------------------------------------------
#define P1BODY(C0, C1, C2, C3, N0, N1, N2, N3, NJ)                             \
    {                                                                          \
        const size_t qnr = (size_t)((NJ) + l31) * CQK;                         \
        N0 = *(const bf16x8*)(qhi + qnr + 8 * h);                              \
        N1 = *(const bf16x8*)(qhi + qnr + 16 + 8 * h);                         \
        N2 = *(const bf16x8*)(qlo + qnr + 8 * h);                              \
        N3 = *(const bf16x8*)(qlo + qnr + 16 + 8 * h);                         \
        f32x16 e0 = {0,0,0,0,0,0,0,0,0,0,0,0,0,0,0,0};                         \
        f32x16 e1 = {0,0,0,0,0,0,0,0,0,0,0,0,0,0,0,0};                         \
        e0 = __builtin_amdgcn_mfma_f32_32x32x16_bf16(C2, bih0, e0, 0, 0, 0);   \
        e1 = __builtin_amdgcn_mfma_f32_32x32x16_bf16(C3, bih1, e1, 0, 0, 0);   \
        e0 = __builtin_amdgcn_mfma_f32_32x32x16_bf16(C0, bil0, e0, 0, 0, 0);   \
        e1 = __builtin_amdgcn_mfma_f32_32x32x16_bf16(C1, bil1, e1, 0, 0, 0);   \
        e0 = __builtin_amdgcn_mfma_f32_32x32x16_bf16(C0, bih0, e0, 0, 0, 0);   \
        e1 = __builtin_amdgcn_mfma_f32_32x32x16_bf16(C1, bih1, e1, 0, 0, 0);   \
        f32x16 ee = e0 + e1;                                                   \
        float a_ = 0.f;                                                        \
        _Pragma("unroll")                                                      \
        for (int r = 0; r < 16; ++r) a_ += fexp2(ee[r]);                       \
        s += a_;                                                               \
    }

__global__ __launch_bounds__(256, 2) void pass1_kernel(
    const unsigned short* __restrict__ qhi,
    const unsigned short* __restrict__ qlo,
    float* __restrict__ ps)
{
    const int t    = threadIdx.x;
    const int lane = t & 63;
    const int w    = t >> 6;
    const int l31  = lane & 31;
    const int h    = lane >> 5;
    const int i0   = (blockIdx.x & 255) * 32;
    const int js   = blockIdx.x >> 8;
    const int JCH  = NN / JS / 4;            // 512 j per wave
    const int jbase = js * (NN / JS) + w * JCH;

    const size_t qir = (size_t)(i0 + l31) * CQK;
    const bf16x8 bih0 = *(const bf16x8*)(qhi + qir + 8 * h);
    const bf16x8 bih1 = *(const bf16x8*)(qhi + qir + 16 + 8 * h);
    const bf16x8 bil0 = *(const bf16x8*)(qlo + qir + 8 * h);
    const bf16x8 bil1 = *(const bf16x8*)(qlo + qir + 16 + 8 * h);

    float s = 0.f;

    bf16x8 qa0, qa1, qa2, qa3, qb0, qb1, qb2, qb3;
    {
        const size_t q0 = (size_t)(jbase + l31) * CQK;
        qa0 = *(const bf16x8*)(qhi + q0 + 8 * h);
        qa1 = *(const bf16x8*)(qhi + q0 + 16 + 8 * h);
        qa2 = *(const bf16x8*)(qlo + q0 + 8 * h);
        qa3 = *(const bf16x8*)(qlo + q0 + 16 + 8 * h);
    }
    for (int st = 0; st < JCH; st += 64) {
        P1BODY(qa0, qa1, qa2, qa3, qb0, qb1, qb2, qb3, jbase + st + 32)
        const int nx = (st + 64 < JCH) ? jbase + st + 64 : jbase + st;
        P1BODY(qb0, qb1, qb2, qb3, qa0, qa1, qa2, qa3, nx)
    }
    s += __shfl_xor(s, 32);      // merge the two h-halves (same i-col)

    __shared__ float rs[4][32];
    if (lane < 32) rs[w][l31] = s;
    __syncthreads();
    if (t < 32) {
        float sf = rs[0][t] + rs[1][t] + rs[2][t] + rs[3][t];
        ps[(size_t)js * NN + i0 + t] = sf;
    }
}

// ---------------------------------------------------------------------------
// Kernel 2b: merge j-split partial sums; bias[i] = log2(sum).
// ---------------------------------------------------------------------------
__global__ __launch_bounds__(256) void finalize_kernel(
    const float* __restrict__ ps, float* __restrict__ bias)
{
    int i = blockIdx.x * 256 + threadIdx.x;
    float s = ps[i];
#pragma unroll
    for (int k = 1; k < JS; ++k) s += ps[(size_t)k * NN + i];
    bias[i] = __builtin_amdgcn_logf(s);   // v_log_f32 = log2
}

// ---------------------------------------------------------------------------
// Kernel 3: barrier-free PV, 1-deep cross-step software pipeline.
// grid: ISPLIT-dep x 256 thr (4 waves). Block: 64 j x 256 c. Wave: 32j x 128c.
// P redistribution: round-3-verified shfl_xor(32)+select.
// __launch_bounds__(256,2): do NOT cap registers (152 unified live; round-6's
// (256,4) cap caused a 255 MB scratch spill).
// ---------------------------------------------------------------------------
#define LOADQ2(N0, N1, N2, N3, NI)                                             \
    {                                                                          \
        const size_t qnr = (size_t)((NI) + l31) * CQK;                         \
        N0 = *(const bf16x8*)(qhi + qnr + 8 * h);                              \
        N1 = *(const bf16x8*)(qhi + qnr + 16 + 8 * h);                         \
        N2 = *(const bf16x8*)(qlo + qnr + 8 * h);                              \
        N3 = *(const bf16x8*)(qlo + qnr + 16 + 8 * h);                         \
    }

#define LOADVF2(VF, I)                                                         \
    _Pragma("unroll")                                                          \
    for (int s2 = 0; s2 < 2; ++s2)                                             \
        _Pragma("unroll")                                                      \
        for (int cf = 0; cf < 4; ++cf)                                         \
            VF[s2][cf] = *(const bf16x8*)(                                     \
                vB + ((size_t)(((I) >> 3) + 2 * s2 + h) * CC + cb + 32 * cf + l31) * 8);

#define LOADB42(B4, I)                                                         \
    _Pragma("unroll")                                                          \
    for (int rg = 0; rg < 4; ++rg)                                             \
        B4[rg] = *(const f32x4*)(bias + (I) + 8 * rg + 4 * h);

// single 6-MFMA accumulate chain: ee = qlo.qjhi + qhi.qjlo + qhi.qjhi
#define ECOMP2(EE, C0, C1, C2, C3)                                             \
    {                                                                          \
        f32x16 z_ = {0,0,0,0,0,0,0,0,0,0,0,0,0,0,0,0};                         \
        z_ = __builtin_amdgcn_mfma_f32_32x32x16_bf16(C3, bjh1, z_, 0, 0, 0);   \
        z_ = __builtin_amdgcn_mfma_f32_32x32x16_bf16(C2, bjh0, z_, 0, 0, 0);   \
        z_ = __builtin_amdgcn_mfma_f32_32x32x16_bf16(C1, bjl1, z_, 0, 0, 0);   \
        z_ = __builtin_amdgcn_mfma_f32_32x32x16_bf16(C0, bjl0, z_, 0, 0, 0);   \
        z_ = __builtin_amdgcn_mfma_f32_32x32x16_bf16(C1, bjh1, z_, 0, 0, 0);   \
        EE = __builtin_amdgcn_mfma_f32_32x32x16_bf16(C0, bjh0, z_, 0, 0, 0);   \
    }

#define FINISH2(EE, B4, VF)                                                    \
    {                                                                          \
        int d0[4], d1[4];                                                      \
        _Pragma("unroll")                                                      \
        for (int rg = 0; rg < 4; ++rg) {                                       \
            float p0 = fexp2(EE[4 * rg + 0] - B4[rg][0]);                      \
            float p1 = fexp2(EE[4 * rg + 1] - B4[rg][1]);                      \
            float p2 = fexp2(EE[4 * rg + 2] - B4[rg][2]);                      \
            float p3 = fexp2(EE[4 * rg + 3] - B4[rg][3]);                      \
            d0[rg] = packbf(p0, p1);                                           \
            d1[rg] = packbf(p2, p3);                                           \
        }                                                                      \
        _Pragma("unroll")                                                      \
        for (int s2 = 0; s2 < 2; ++s2) {                                       \
            const int a_ = d0[2 * s2], b_ = d0[2 * s2 + 1];                    \
            const int c_ = d1[2 * s2], d_ = d1[2 * s2 + 1];                    \
            const int pa = __shfl_xor(a_, 32);                                 \
            const int pb = __shfl_xor(b_, 32);                                 \
            const int pc = __shfl_xor(c_, 32);                                 \
            const int pd = __shfl_xor(d_, 32);                                 \
            union { int i[4]; bf16x8 v; } pf;                                  \
            pf.i[0] = h ? pb : a_;                                             \
            pf.i[1] = h ? pd : c_;                                             \
            pf.i[2] = h ? b_ : pa;                                             \
            pf.i[3] = h ? d_ : pc;                                             \
            _Pragma("unroll")                                                  \
            for (int cf = 0; cf < 4; ++cf)                                     \
                acc[cf] = __builtin_amdgcn_mfma_f32_32x32x16_bf16(             \
                    pf.v, VF[s2][cf], acc[cf], 0, 0, 0);                       \
        }                                                                      \
    }

template<int ISPLIT, bool DIRECT>
__global__ __launch_bounds__(256, 2) void pass2_kernel(
    const unsigned short* __restrict__ qhi,
    const unsigned short* __restrict__ qlo,
    const unsigned short* __restrict__ vB,
    const float* __restrict__ bias,
    const float* __restrict__ f,
    const float* __restrict__ gp,
    float* __restrict__ dst)
{
    const int t    = threadIdx.x;
    const int lane = t & 63;
    const int w    = t >> 6;
    const int l31  = lane & 31;
    const int h    = lane >> 5;

    int jblk, isp;
    if (ISPLIT == 8) {
        // one isp per XCD: its vB slice (512 KB) + q slice stay L2-resident
        isp  = blockIdx.x & 7;
        jblk = blockIdx.x >> 3;                 // 0..127
    } else if (ISPLIT == 4) {
        const int bid = blockIdx.x;
        isp  = (bid & 7) >> 1;
        jblk = ((bid >> 3) << 1) | (bid & 1);   // 0..127, bijective
    } else if (ISPLIT == 2) {
        isp  = blockIdx.x & 1;
        jblk = blockIdx.x >> 1;
    } else {
        isp  = 0;
        jblk = blockIdx.x;
    }
    const int jb   = jblk * 64;
    const int jw   = w & 1, cw = w >> 1;
    const int jrow = jb + 32 * jw;
    const int cb   = 128 * cw;
    const int IL   = NN / ISPLIT;
    const int ibase = isp * IL;
    const int iend  = ibase + IL;

    const size_t qjr = (size_t)(jrow + l31) * CQK;
    const bf16x8 bjh0 = *(const bf16x8*)(qhi + qjr + 8 * h);
    const bf16x8 bjh1 = *(const bf16x8*)(qhi + qjr + 16 + 8 * h);
    const bf16x8 bjl0 = *(const bf16x8*)(qlo + qjr + 8 * h);
    const bf16x8 bjl1 = *(const bf16x8*)(qlo + qjr + 16 + 8 * h);

    f32x16 acc[4];
#pragma unroll
    for (int cf = 0; cf < 4; ++cf)
#pragma unroll
        for (int r = 0; r < 16; ++r) acc[cf][r] = 0.f;

    f32x16 eeA, eeB;
    f32x4  b4A[4], b4B[4];
    bf16x8 qa0, qa1, qa2, qa3, qb0, qb1, qb2, qb3;
    bf16x8 vf[2][4];

    // prologue: E(step0) ready in eeA; qb/b4B staged for step1
    LOADQ2(qa0, qa1, qa2, qa3, ibase)
    LOADB42(b4A, ibase)
    ECOMP2(eeA, qa0, qa1, qa2, qa3)
    LOADQ2(qb0, qb1, qb2, qb3, ibase + 32)
    LOADB42(b4B, ibase + 32)

    for (int i0s = ibase; i0s < iend; i0s += 64) {
        const int n1 = (i0s + 64 < iend) ? i0s + 64 : ibase;   // clamp: extra
        const int n2 = (i0s + 96 < iend) ? i0s + 96 : ibase;   // E discarded
        // stage A: E(i0s+32) in flight over FINISH(i0s)
        LOADVF2(vf, i0s)
        ECOMP2(eeB, qb0, qb1, qb2, qb3)
        LOADQ2(qa0, qa1, qa2, qa3, n1)
        FINISH2(eeA, b4A, vf)
        LOADB42(b4A, n1)
        // stage B: E(i0s+64) in flight over FINISH(i0s+32)
        LOADVF2(vf, i0s + 32)
        ECOMP2(eeA, qa0, qa1, qa2, qa3)
        LOADQ2(qb0, qb1, qb2, qb3, n2)
        FINISH2(eeB, b4B, vf)
        LOADB42(b4B, n2)
    }

    if (DIRECT) {
        const float g = gp[0];
#pragma unroll
        for (int cf = 0; cf < 4; ++cf) {
            const int c = cb + 32 * cf + l31;
#pragma unroll
            for (int rg = 0; rg < 4; ++rg)
#pragma unroll
                for (int r = 0; r < 4; ++r) {
                    const int j = jrow + 4 * h + r + 8 * rg;
                    dst[(size_t)j * CC + c] =
                        fmaf(g, acc[cf][4 * rg + r], f[(size_t)j * CC + c]);
                }
        }
    } else {
        float* part = dst + (size_t)isp * NN * CC;
#pragma unroll
        for (int cf = 0; cf < 4; ++cf) {
            const int c = cb + 32 * cf + l31;
#pragma unroll
            for (int rg = 0; rg < 4; ++rg)
#pragma unroll
                for (int r = 0; r < 4; ++r) {
                    const int j = jrow + 4 * h + r + 8 * rg;
                    part[(size_t)j * CC + c] = acc[cf][4 * rg + r];
                }
        }
    }
}

// ---------------------------------------------------------------------------
// Kernel 4: out = gamma * sum_splits(part) + f
// ---------------------------------------------------------------------------
template<int SPLIT>
__global__ __launch_bounds__(256) void reduce_kernel(
    const float* __restrict__ part, const float* __restrict__ f,
    const float* __restrict__ gp, float* __restrict__ out)
{
    size_t idx = (size_t)blockIdx.x * 256 + threadIdx.x;   // f32x4 units
    const f32x4* p4 = (const f32x4*)part;
    f32x4 s = p4[idx];
#pragma unroll
    for (int k = 1; k < SPLIT; ++k) s += p4[(size_t)k * (NN * CC / 4) + idx];
    f32x4 fv = ((const f32x4*)f)[idx];
    float g = gp[0];
    f32x4 o;
#pragma unroll
    for (int r = 0; r < 4; ++r) o[r] = fmaf(g, s[r], fv[r]);
    ((f32x4*)out)[idx] = o;
}

// ---------------------------------------------------------------------------
extern "C" void kernel_launch(void* const* d_in, const int* in_sizes, int n_in,
                              void* d_out, int out_size, void* d_ws, size_t ws_size,
                              hipStream_t stream) {
    const float* f     = (const float*)d_in[0];
    const float* Wqk   = (const float*)d_in[1];
    const float* Wv    = (const float*)d_in[2];
    const float* bv    = (const float*)d_in[3];
    const float* gamma = (const float*)d_in[4];
    float* out = (float*)d_out;

    char* ws = (char*)d_ws;
    unsigned short* qhi = (unsigned short*)ws;                         // 512 KB
    unsigned short* qlo = (unsigned short*)(ws + (512 << 10));         // 512 KB
    unsigned short* vB  = (unsigned short*)(ws + (1 << 20));           // 4 MB
    float* ps   = (float*)(ws + (5 << 20));                            // 128 KB
    float* bias = (float*)(ws + (5 << 20) + (256 << 10));              // 32 KB
    float* part = (float*)(ws + (6 << 20));                            // ISPLIT*8 MB

    proj_q_kernel<<<dim3(NN / 8), dim3(256), 0, stream>>>(f, Wqk, qhi, qlo);
    proj_v_kernel<<<dim3(NN / 32), dim3(256), 0, stream>>>(f, Wv, bv, vB);
    pass1_kernel<<<dim3((NN / 32) * JS), dim3(256), 0, stream>>>(qhi, qlo, ps);
    finalize_kernel<<<dim3(NN / 256), dim3(256), 0, stream>>>(ps, bias);

    const size_t PB = (size_t)NN * CC * 4;   // one partial buffer: 8 MB
    const size_t B0 = (size_t)6 << 20;
    if (ws_size >= B0 + 8 * PB) {
        pass2_kernel<8, false><<<dim3(128 * 8), dim3(256), 0, stream>>>(qhi, qlo, vB, bias, f, gamma, part);
        reduce_kernel<8><<<dim3(NN * CC / 1024), dim3(256), 0, stream>>>(part, f, gamma, out);
    } else if (ws_size >= B0 + 4 * PB) {
        pass2_kernel<4, false><<<dim3(128 * 4), dim3(256), 0, stream>>>(qhi, qlo, vB, bias, f, gamma, part);
        reduce_kernel<4><<<dim3(NN * CC / 1024), dim3(256), 0, stream>>>(part, f, gamma, out);
    } else if (ws_size >= B0 + 2 * PB) {
        pass2_kernel<2, false><<<dim3(128 * 2), dim3(256), 0, stream>>>(qhi, qlo, vB, bias, f, gamma, part);
        reduce_kernel<2><<<dim3(NN * CC / 1024), dim3(256), 0, stream>>>(part, f, gamma, out);
    } else if (ws_size >= B0 + 1 * PB) {
        pass2_kernel<1, false><<<dim3(128), dim3(256), 0, stream>>>(qhi, qlo, vB, bias, f, gamma, part);
        reduce_kernel<1><<<dim3(NN * CC / 1024), dim3(256), 0, stream>>>(part, f, gamma, out);
    } else {
        pass2_kernel<1, true><<<dim3(128), dim3(256), 0, stream>>>(qhi, qlo, vB, bias, f, gamma, out);
    }
}

// Round 9
// 160.780 us; speedup vs baseline: 1.0589x; 1.0589x over previous
//
#include <hip/hip_runtime.h>
#include <hip/hip_bf16.h>

#define NN 8192
#define CC 256
#define CQK 32
#define JS 4   // pass1 j-splits

using bf16x8 = __attribute__((ext_vector_type(8))) short;
using s16x4  = __attribute__((ext_vector_type(4))) short;
using f32x4  = __attribute__((ext_vector_type(4))) float;
using f32x16 = __attribute__((ext_vector_type(16))) float;

static __device__ __forceinline__ unsigned short f2bf(float x) {
    union { __hip_bfloat16 h; unsigned short u; } cv;
    cv.h = __float2bfloat16(x);
    return cv.u;
}
static __device__ __forceinline__ float bf2f(unsigned short u) {
    union { unsigned short u; __hip_bfloat16 h; } cv;
    cv.u = u;
    return __bfloat162float(cv.h);
}
static __device__ __forceinline__ float fexp2(float x) { return __builtin_amdgcn_exp2f(x); }
static __device__ __forceinline__ int packbf(float lo, float hi) {
    return (int)f2bf(lo) | ((int)f2bf(hi) << 16);
}

// ---------------------------------------------------------------------------
// Kernel 1a: q = (f @ Wqk^T) * sqrt(log2 e), stored hi/lo bf16.
// ---------------------------------------------------------------------------
__global__ __launch_bounds__(256) void proj_q_kernel(
    const float* __restrict__ f, const float* __restrict__ Wqk,
    unsigned short* __restrict__ qhi, unsigned short* __restrict__ qlo)
{
    __shared__ __align__(16) float fl[8][CC];
    const int t  = threadIdx.x;
    const int r0 = blockIdx.x * 8;
    {
        const float4* src = (const float4*)(f + (size_t)r0 * CC);
        float4* dst = (float4*)&fl[0][0];
        dst[t]       = src[t];
        dst[t + 256] = src[t + 256];
    }
    __syncthreads();
    const int cq = t & 31;
    const int rg = t >> 5;
    const float4* w4 = (const float4*)(Wqk + (size_t)cq * CC);
    float a = 0.f;
    for (int k4 = 0; k4 < 64; ++k4) {
        float4 wq = w4[k4];
        const float4 fv = *(const float4*)&fl[rg][k4 * 4];
        a = fmaf(wq.x, fv.x, a);
        a = fmaf(wq.y, fv.y, a);
        a = fmaf(wq.z, fv.z, a);
        a = fmaf(wq.w, fv.w, a);
    }
    a *= 1.2011224087864498f;              // sqrt(log2 e) -> exp2 domain
    unsigned short hh = f2bf(a);
    unsigned short ll = f2bf(a - bf2f(hh));
    qhi[(size_t)(r0 + rg) * CQK + cq] = hh;
    qlo[(size_t)(r0 + rg) * CQK + cq] = ll;
}

// ---------------------------------------------------------------------------
// Kernel 1b: v = f @ Wv^T + bv via bf16 32x32x16 MFMA.
// Output layout vB[i>>3][c][i&7] bf16 -> PV B-frags are coalesced b128 loads.
// ---------------------------------------------------------------------------
__global__ __launch_bounds__(256, 4) void proj_v_kernel(
    const float* __restrict__ f, const float* __restrict__ Wv,
    const float* __restrict__ bv, unsigned short* __restrict__ vB)
{
    const int t    = threadIdx.x;
    const int lane = t & 63;
    const int w    = t >> 6;
    const int l31  = lane & 31;
    const int h    = lane >> 5;
    const int nb   = blockIdx.x * 32;
    const int cb   = w * 64;

    f32x16 acc[2];
#pragma unroll
    for (int cf = 0; cf < 2; ++cf)
#pragma unroll
        for (int r = 0; r < 16; ++r) acc[cf][r] = 0.f;

    const float* frow = f + (size_t)(nb + l31) * CC;
#pragma unroll
    for (int ks = 0; ks < 16; ++ks) {
        const int k0 = ks * 16 + 8 * h;
        float4 a0 = *(const float4*)(frow + k0);
        float4 a1 = *(const float4*)(frow + k0 + 4);
        bf16x8 af;
        af[0] = (short)f2bf(a0.x); af[1] = (short)f2bf(a0.y);
        af[2] = (short)f2bf(a0.z); af[3] = (short)f2bf(a0.w);
        af[4] = (short)f2bf(a1.x); af[5] = (short)f2bf(a1.y);
        af[6] = (short)f2bf(a1.z); af[7] = (short)f2bf(a1.w);
#pragma unroll
        for (int cf = 0; cf < 2; ++cf) {
            const float* wrow = Wv + (size_t)(cb + 32 * cf + l31) * CC + k0;
            float4 b0 = *(const float4*)(wrow);
            float4 b1 = *(const float4*)(wrow + 4);
            bf16x8 bw;
            bw[0] = (short)f2bf(b0.x); bw[1] = (short)f2bf(b0.y);
            bw[2] = (short)f2bf(b0.z); bw[3] = (short)f2bf(b0.w);
            bw[4] = (short)f2bf(b1.x); bw[5] = (short)f2bf(b1.y);
            bw[6] = (short)f2bf(b1.z); bw[7] = (short)f2bf(b1.w);
            acc[cf] = __builtin_amdgcn_mfma_f32_32x32x16_bf16(af, bw, acc[cf], 0, 0, 0);
        }
    }
#pragma unroll
    for (int cf = 0; cf < 2; ++cf) {
        const int cg = cb + 32 * cf + l31;
        const float bvc = bv[cg];
#pragma unroll
        for (int rg = 0; rg < 4; ++rg) {
            const int ib = (nb >> 3) + rg;
            s16x4 pk;
#pragma unroll
            for (int r = 0; r < 4; ++r)
                pk[r] = (short)f2bf(acc[cf][4 * rg + r] + bvc);
            *(s16x4*)(vB + ((size_t)ib * CC + cg) * 8 + 4 * h) = pk;
        }
    }
}

// ---------------------------------------------------------------------------
// Kernel 2: per-i partial denominators over a j-range. NO max tracking
// (exp2-domain energies bounded, f32-safe).
// grid (NN/32)*JS x 256 thr (4 waves, each 1/(4*JS) of j).
// ---------------------------------------------------------------------------
#define P1BODY(C0, C1, C2, C3, N0, N1, N2, N3, NJ)                             \
    {                                                                          \
        const size_t qnr = (size_t)((NJ) + l31) * CQK;                         \
        N0 = *(const bf16x8*)(qhi + qnr + 8 * h);                              \
        N1 = *(const bf16x8*)(qhi + qnr + 16 + 8 * h);                         \
        N2 = *(const bf16x8*)(qlo + qnr + 8 * h);                              \
        N3 = *(const bf16x8*)(qlo + qnr + 16 + 8 * h);                         \
        f32x16 e0 = {0,0,0,0,0,0,0,0,0,0,0,0,0,0,0,0};                         \
        f32x16 e1 = {0,0,0,0,0,0,0,0,0,0,0,0,0,0,0,0};                         \
        e0 = __builtin_amdgcn_mfma_f32_32x32x16_bf16(C2, bih0, e0, 0, 0, 0);   \
        e1 = __builtin_amdgcn_mfma_f32_32x32x16_bf16(C3, bih1, e1, 0, 0, 0);   \
        e0 = __builtin_amdgcn_mfma_f32_32x32x16_bf16(C0, bil0, e0, 0, 0, 0);   \
        e1 = __builtin_amdgcn_mfma_f32_32x32x16_bf16(C1, bil1, e1, 0, 0, 0);   \
        e0 = __builtin_amdgcn_mfma_f32_32x32x16_bf16(C0, bih0, e0, 0, 0, 0);   \
        e1 = __builtin_amdgcn_mfma_f32_32x32x16_bf16(C1, bih1, e1, 0, 0, 0);   \
        f32x16 ee = e0 + e1;                                                   \
        float a_ = 0.f;                                                        \
        _Pragma("unroll")                                                      \
        for (int r = 0; r < 16; ++r) a_ += fexp2(ee[r]);                       \
        s += a_;                                                               \
    }

__global__ __launch_bounds__(256, 2) void pass1_kernel(
    const unsigned short* __restrict__ qhi,
    const unsigned short* __restrict__ qlo,
    float* __restrict__ ps)
{
    const int t    = threadIdx.x;
    const int lane = t & 63;
    const int w    = t >> 6;
    const int l31  = lane & 31;
    const int h    = lane >> 5;
    const int i0   = (blockIdx.x & 255) * 32;
    const int js   = blockIdx.x >> 8;
    const int JCH  = NN / JS / 4;            // 512 j per wave
    const int jbase = js * (NN / JS) + w * JCH;

    const size_t qir = (size_t)(i0 + l31) * CQK;
    const bf16x8 bih0 = *(const bf16x8*)(qhi + qir + 8 * h);
    const bf16x8 bih1 = *(const bf16x8*)(qhi + qir + 16 + 8 * h);
    const bf16x8 bil0 = *(const bf16x8*)(qlo + qir + 8 * h);
    const bf16x8 bil1 = *(const bf16x8*)(qlo + qir + 16 + 8 * h);

    float s = 0.f;

    bf16x8 qa0, qa1, qa2, qa3, qb0, qb1, qb2, qb3;
    {
        const size_t q0 = (size_t)(jbase + l31) * CQK;
        qa0 = *(const bf16x8*)(qhi + q0 + 8 * h);
        qa1 = *(const bf16x8*)(qhi + q0 + 16 + 8 * h);
        qa2 = *(const bf16x8*)(qlo + q0 + 8 * h);
        qa3 = *(const bf16x8*)(qlo + q0 + 16 + 8 * h);
    }
    for (int st = 0; st < JCH; st += 64) {
        P1BODY(qa0, qa1, qa2, qa3, qb0, qb1, qb2, qb3, jbase + st + 32)
        const int nx = (st + 64 < JCH) ? jbase + st + 64 : jbase + st;
        P1BODY(qb0, qb1, qb2, qb3, qa0, qa1, qa2, qa3, nx)
    }
    s += __shfl_xor(s, 32);      // merge the two h-halves (same i-col)

    __shared__ float rs[4][32];
    if (lane < 32) rs[w][l31] = s;
    __syncthreads();
    if (t < 32) {
        float sf = rs[0][t] + rs[1][t] + rs[2][t] + rs[3][t];
        ps[(size_t)js * NN + i0 + t] = sf;
    }
}

// ---------------------------------------------------------------------------
// Kernel 2b: merge j-split partial sums; bias[i] = log2(sum).
// ---------------------------------------------------------------------------
__global__ __launch_bounds__(256) void finalize_kernel(
    const float* __restrict__ ps, float* __restrict__ bias)
{
    int i = blockIdx.x * 256 + threadIdx.x;
    float s = ps[i];
#pragma unroll
    for (int k = 1; k < JS; ++k) s += ps[(size_t)k * NN + i];
    bias[i] = __builtin_amdgcn_logf(s);   // v_log_f32 = log2
}

// ---------------------------------------------------------------------------
// Kernel 3: barrier-free PV, cross-step pipeline with DOUBLE-BUFFERED q, bias,
// and vf (V-fragments). vf single-buffering created a WAR hazard: the next
// half-step's vf loads couldn't issue until PV consumed the previous ones,
// exposing ~300 cyc of L2 latency twice per 64-i iter. vfA/vfB break it.
// grid 512 x 256 thr (4 waves). Block: 64 j x 256 c. Wave: 32j x 128c.
// __launch_bounds__(256,2): do NOT cap registers (r6 lesson: (256,4) -> spill).
// ---------------------------------------------------------------------------
#define LOADQ2(N0, N1, N2, N3, NI)                                             \
    {                                                                          \
        const size_t qnr = (size_t)((NI) + l31) * CQK;                         \
        N0 = *(const bf16x8*)(qhi + qnr + 8 * h);                              \
        N1 = *(const bf16x8*)(qhi + qnr + 16 + 8 * h);                         \
        N2 = *(const bf16x8*)(qlo + qnr + 8 * h);                              \
        N3 = *(const bf16x8*)(qlo + qnr + 16 + 8 * h);                         \
    }

#define LOADVF2(VF, I)                                                         \
    _Pragma("unroll")                                                          \
    for (int s2 = 0; s2 < 2; ++s2)                                             \
        _Pragma("unroll")                                                      \
        for (int cf = 0; cf < 4; ++cf)                                         \
            VF[s2][cf] = *(const bf16x8*)(                                     \
                vB + ((size_t)(((I) >> 3) + 2 * s2 + h) * CC + cb + 32 * cf + l31) * 8);

#define LOADB42(B4, I)                                                         \
    _Pragma("unroll")                                                          \
    for (int rg = 0; rg < 4; ++rg)                                             \
        B4[rg] = *(const f32x4*)(bias + (I) + 8 * rg + 4 * h);

// single 6-MFMA accumulate chain: ee = qlo.qjhi + qhi.qjlo + qhi.qjhi
#define ECOMP2(EE, C0, C1, C2, C3)                                             \
    {                                                                          \
        f32x16 z_ = {0,0,0,0,0,0,0,0,0,0,0,0,0,0,0,0};                         \
        z_ = __builtin_amdgcn_mfma_f32_32x32x16_bf16(C3, bjh1, z_, 0, 0, 0);   \
        z_ = __builtin_amdgcn_mfma_f32_32x32x16_bf16(C2, bjh0, z_, 0, 0, 0);   \
        z_ = __builtin_amdgcn_mfma_f32_32x32x16_bf16(C1, bjl1, z_, 0, 0, 0);   \
        z_ = __builtin_amdgcn_mfma_f32_32x32x16_bf16(C0, bjl0, z_, 0, 0, 0);   \
        z_ = __builtin_amdgcn_mfma_f32_32x32x16_bf16(C1, bjh1, z_, 0, 0, 0);   \
        EE = __builtin_amdgcn_mfma_f32_32x32x16_bf16(C0, bjh0, z_, 0, 0, 0);   \
    }

#define FINISH2(EE, B4, VF)                                                    \
    {                                                                          \
        int d0[4], d1[4];                                                      \
        _Pragma("unroll")                                                      \
        for (int rg = 0; rg < 4; ++rg) {                                       \
            float p0 = fexp2(EE[4 * rg + 0] - B4[rg][0]);                      \
            float p1 = fexp2(EE[4 * rg + 1] - B4[rg][1]);                      \
            float p2 = fexp2(EE[4 * rg + 2] - B4[rg][2]);                      \
            float p3 = fexp2(EE[4 * rg + 3] - B4[rg][3]);                      \
            d0[rg] = packbf(p0, p1);                                           \
            d1[rg] = packbf(p2, p3);                                           \
        }                                                                      \
        _Pragma("unroll")                                                      \
        for (int s2 = 0; s2 < 2; ++s2) {                                       \
            const int a_ = d0[2 * s2], b_ = d0[2 * s2 + 1];                    \
            const int c_ = d1[2 * s2], d_ = d1[2 * s2 + 1];                    \
            const int pa = __shfl_xor(a_, 32);                                 \
            const int pb = __shfl_xor(b_, 32);                                 \
            const int pc = __shfl_xor(c_, 32);                                 \
            const int pd = __shfl_xor(d_, 32);                                 \
            union { int i[4]; bf16x8 v; } pf;                                  \
            pf.i[0] = h ? pb : a_;                                             \
            pf.i[1] = h ? pd : c_;                                             \
            pf.i[2] = h ? b_ : pa;                                             \
            pf.i[3] = h ? d_ : pc;                                             \
            _Pragma("unroll")                                                  \
            for (int cf = 0; cf < 4; ++cf)                                     \
                acc[cf] = __builtin_amdgcn_mfma_f32_32x32x16_bf16(             \
                    pf.v, VF[s2][cf], acc[cf], 0, 0, 0);                       \
        }                                                                      \
    }

template<int ISPLIT, bool DIRECT>
__global__ __launch_bounds__(256, 2) void pass2_kernel(
    const unsigned short* __restrict__ qhi,
    const unsigned short* __restrict__ qlo,
    const unsigned short* __restrict__ vB,
    const float* __restrict__ bias,
    const float* __restrict__ f,
    const float* __restrict__ gp,
    float* __restrict__ dst)
{
    const int t    = threadIdx.x;
    const int lane = t & 63;
    const int w    = t >> 6;
    const int l31  = lane & 31;
    const int h    = lane >> 5;

    int jblk, isp;
    if (ISPLIT == 4) {
        // XCD-aware: each XCD pair owns one isp -> its vB slice stays in L2
        const int bid = blockIdx.x;
        isp  = (bid & 7) >> 1;
        jblk = ((bid >> 3) << 1) | (bid & 1);   // 0..127, bijective
    } else if (ISPLIT == 2) {
        isp  = blockIdx.x & 1;
        jblk = blockIdx.x >> 1;
    } else {
        isp  = 0;
        jblk = blockIdx.x;
    }
    const int jb   = jblk * 64;
    const int jw   = w & 1, cw = w >> 1;
    const int jrow = jb + 32 * jw;
    const int cb   = 128 * cw;
    const int IL   = NN / ISPLIT;
    const int ibase = isp * IL;
    const int iend  = ibase + IL;

    const size_t qjr = (size_t)(jrow + l31) * CQK;
    const bf16x8 bjh0 = *(const bf16x8*)(qhi + qjr + 8 * h);
    const bf16x8 bjh1 = *(const bf16x8*)(qhi + qjr + 16 + 8 * h);
    const bf16x8 bjl0 = *(const bf16x8*)(qlo + qjr + 8 * h);
    const bf16x8 bjl1 = *(const bf16x8*)(qlo + qjr + 16 + 8 * h);

    f32x16 acc[4];
#pragma unroll
    for (int cf = 0; cf < 4; ++cf)
#pragma unroll
        for (int r = 0; r < 16; ++r) acc[cf][r] = 0.f;

    f32x16 eeA, eeB;
    f32x4  b4A[4], b4B[4];
    bf16x8 qa0, qa1, qa2, qa3, qb0, qb1, qb2, qb3;
    bf16x8 vfA[2][4], vfB[2][4];

    // prologue: E(step0) ready in eeA; qb/b4B staged for step1; vfA for step0
    LOADQ2(qa0, qa1, qa2, qa3, ibase)
    LOADB42(b4A, ibase)
    LOADVF2(vfA, ibase)
    ECOMP2(eeA, qa0, qa1, qa2, qa3)
    LOADQ2(qb0, qb1, qb2, qb3, ibase + 32)
    LOADB42(b4B, ibase + 32)

    for (int i0s = ibase; i0s < iend; i0s += 64) {
        const int n1 = (i0s + 64 < iend) ? i0s + 64 : ibase;   // clamp: extra
        const int n2 = (i0s + 96 < iend) ? i0s + 96 : ibase;   // work discarded
        // stage A: E(i0s+32) + vf(i0s+32) in flight over FINISH(i0s)
        LOADVF2(vfB, i0s + 32)
        ECOMP2(eeB, qb0, qb1, qb2, qb3)
        LOADQ2(qa0, qa1, qa2, qa3, n1)
        FINISH2(eeA, b4A, vfA)
        LOADB42(b4A, n1)
        // stage B: E(i0s+64) + vf(i0s+64) in flight over FINISH(i0s+32)
        LOADVF2(vfA, n1)
        ECOMP2(eeA, qa0, qa1, qa2, qa3)
        LOADQ2(qb0, qb1, qb2, qb3, n2)
        FINISH2(eeB, b4B, vfB)
        LOADB42(b4B, n2)
    }

    if (DIRECT) {
        const float g = gp[0];
#pragma unroll
        for (int cf = 0; cf < 4; ++cf) {
            const int c = cb + 32 * cf + l31;
#pragma unroll
            for (int rg = 0; rg < 4; ++rg)
#pragma unroll
                for (int r = 0; r < 4; ++r) {
                    const int j = jrow + 4 * h + r + 8 * rg;
                    dst[(size_t)j * CC + c] =
                        fmaf(g, acc[cf][4 * rg + r], f[(size_t)j * CC + c]);
                }
        }
    } else {
        float* part = dst + (size_t)isp * NN * CC;
#pragma unroll
        for (int cf = 0; cf < 4; ++cf) {
            const int c = cb + 32 * cf + l31;
#pragma unroll
            for (int rg = 0; rg < 4; ++rg)
#pragma unroll
                for (int r = 0; r < 4; ++r) {
                    const int j = jrow + 4 * h + r + 8 * rg;
                    part[(size_t)j * CC + c] = acc[cf][4 * rg + r];
                }
        }
    }
}

// ---------------------------------------------------------------------------
// Kernel 4: out = gamma * sum_splits(part) + f
// ---------------------------------------------------------------------------
template<int SPLIT>
__global__ __launch_bounds__(256) void reduce_kernel(
    const float* __restrict__ part, const float* __restrict__ f,
    const float* __restrict__ gp, float* __restrict__ out)
{
    size_t idx = (size_t)blockIdx.x * 256 + threadIdx.x;   // f32x4 units
    const f32x4* p4 = (const f32x4*)part;
    f32x4 s = p4[idx];
#pragma unroll
    for (int k = 1; k < SPLIT; ++k) s += p4[(size_t)k * (NN * CC / 4) + idx];
    f32x4 fv = ((const f32x4*)f)[idx];
    float g = gp[0];
    f32x4 o;
#pragma unroll
    for (int r = 0; r < 4; ++r) o[r] = fmaf(g, s[r], fv[r]);
    ((f32x4*)out)[idx] = o;
}

// ---------------------------------------------------------------------------
extern "C" void kernel_launch(void* const* d_in, const int* in_sizes, int n_in,
                              void* d_out, int out_size, void* d_ws, size_t ws_size,
                              hipStream_t stream) {
    const float* f     = (const float*)d_in[0];
    const float* Wqk   = (const float*)d_in[1];
    const float* Wv    = (const float*)d_in[2];
    const float* bv    = (const float*)d_in[3];
    const float* gamma = (const float*)d_in[4];
    float* out = (float*)d_out;

    char* ws = (char*)d_ws;
    unsigned short* qhi = (unsigned short*)ws;                         // 512 KB
    unsigned short* qlo = (unsigned short*)(ws + (512 << 10));         // 512 KB
    unsigned short* vB  = (unsigned short*)(ws + (1 << 20));           // 4 MB
    float* ps   = (float*)(ws + (5 << 20));                            // 128 KB
    float* bias = (float*)(ws + (5 << 20) + (256 << 10));              // 32 KB
    float* part = (float*)(ws + (6 << 20));                            // ISPLIT*8 MB

    proj_q_kernel<<<dim3(NN / 8), dim3(256), 0, stream>>>(f, Wqk, qhi, qlo);
    proj_v_kernel<<<dim3(NN / 32), dim3(256), 0, stream>>>(f, Wv, bv, vB);
    pass1_kernel<<<dim3((NN / 32) * JS), dim3(256), 0, stream>>>(qhi, qlo, ps);
    finalize_kernel<<<dim3(NN / 256), dim3(256), 0, stream>>>(ps, bias);

    const size_t PB = (size_t)NN * CC * 4;   // one partial buffer: 8 MB
    const size_t B0 = (size_t)6 << 20;
    if (ws_size >= B0 + 4 * PB) {
        pass2_kernel<4, false><<<dim3(128 * 4), dim3(256), 0, stream>>>(qhi, qlo, vB, bias, f, gamma, part);
        reduce_kernel<4><<<dim3(NN * CC / 1024), dim3(256), 0, stream>>>(part, f, gamma, out);
    } else if (ws_size >= B0 + 2 * PB) {
        pass2_kernel<2, false><<<dim3(128 * 2), dim3(256), 0, stream>>>(qhi, qlo, vB, bias, f, gamma, part);
        reduce_kernel<2><<<dim3(NN * CC / 1024), dim3(256), 0, stream>>>(part, f, gamma, out);
    } else if (ws_size >= B0 + 1 * PB) {
        pass2_kernel<1, false><<<dim3(128), dim3(256), 0, stream>>>(qhi, qlo, vB, bias, f, gamma, part);
        reduce_kernel<1><<<dim3(NN * CC / 1024), dim3(256), 0, stream>>>(part, f, gamma, out);
    } else {
        pass2_kernel<1, true><<<dim3(128), dim3(256), 0, stream>>>(qhi, qlo, vB, bias, f, gamma, out);
    }
}